// Round 1
// baseline (474.642 us; speedup 1.0000x reference)
//
#include <hip/hip_runtime.h>
#include <math.h>

// AxialAttention on MI355X — round 0 baseline (all fp32).
// K1: QKV 1x1-conv GEMM + BN -> q/k/v in [b][g][row][c] layout (workspace).
// K2: fused per-(b,i,g) attention: s[j,w] in LDS, softmax over w, sv+sve+BN.

static constexpr int NB    = 32;
static constexpr int HH    = 56;
static constexpr int CIN   = 128;
static constexpr int GG    = 8;
static constexpr int PLANE = HH * HH;          // 3136
static constexpr int M_ROWS = NB * PLANE;      // 100352

// -------------------------------------------------------------------------
// Kernel 1: out[m, d] = BN(x[m, :] @ W[:, d]) for d in [0,256) = [q|k|v]
// Block: 32 rows x 256 cols, K=128 in 4 chunks of 32. Thread: 4 rows x 8 cols.
// -------------------------------------------------------------------------
__global__ __launch_bounds__(256) void qkv_kernel(
    const float* __restrict__ x,
    const float* __restrict__ wq, const float* __restrict__ wk, const float* __restrict__ wv,
    const float* __restrict__ gq, const float* __restrict__ bq,
    const float* __restrict__ gk, const float* __restrict__ bk,
    const float* __restrict__ gv, const float* __restrict__ bv,
    float* __restrict__ qt, float* __restrict__ kt, float* __restrict__ vt)
{
    __shared__ float xs[32][32];    // [row][kchunk]
    __shared__ float ws[32][256];   // [kchunk][col]

    const int t  = threadIdx.x;
    const int m0 = blockIdx.x * 32;
    const int tc = t & 31;          // col lane: cols d = tc + 32*m
    const int tr = t >> 5;          // row group: rows 4*tr + i

    // per-thread weight column pointer (col index == t for the staging loop)
    const float* wptr;
    int wstride;
    if (t < 64)       { wptr = wq + t;         wstride = 64;  }
    else if (t < 128) { wptr = wk + (t - 64);  wstride = 64;  }
    else              { wptr = wv + (t - 128); wstride = 128; }

    float acc[4][8];
    #pragma unroll
    for (int i = 0; i < 4; ++i)
        #pragma unroll
        for (int m = 0; m < 8; ++m) acc[i][m] = 0.f;

    for (int k0 = 0; k0 < 128; k0 += 32) {
        #pragma unroll
        for (int n = 0; n < 4; ++n)
            xs[tr + 8 * n][tc] = x[(m0 + tr + 8 * n) * CIN + k0 + tc];
        #pragma unroll 8
        for (int n = 0; n < 32; ++n)
            ws[n][t] = wptr[(size_t)(k0 + n) * wstride];
        __syncthreads();

        #pragma unroll
        for (int c = 0; c < 32; ++c) {
            float xv[4];
            #pragma unroll
            for (int i = 0; i < 4; ++i) xv[i] = xs[4 * tr + i][c];
            #pragma unroll
            for (int m = 0; m < 8; ++m) {
                float wvv = ws[c][tc + 32 * m];
                #pragma unroll
                for (int i = 0; i < 4; ++i)
                    acc[i][m] = fmaf(xv[i], wvv, acc[i][m]);
            }
        }
        __syncthreads();
    }

    const float inv = 1.0f / sqrtf(1.001f);   // BN: mean=0, var=1, eps=1e-3

    #pragma unroll
    for (int m = 0; m < 8; ++m) {
        const int d = tc + 32 * m;            // uniform across the wave
        float scale, shift;
        if (d < 64)        { scale = gq[d] * inv;       shift = bq[d]; }
        else if (d < 128)  { scale = gk[d - 64] * inv;  shift = bk[d - 64]; }
        else               { scale = gv[d - 128] * inv; shift = bv[d - 128]; }
        #pragma unroll
        for (int i = 0; i < 4; ++i) {
            const int mr  = m0 + 4 * tr + i;
            const int b   = mr / PLANE;
            const int rem = mr - b * PLANE;   // = i_h*56 + w
            const float val = fmaf(acc[i][m], scale, shift);
            if (d < 64) {
                const int g = d >> 3, c8 = d & 7;
                qt[((b * GG + g) * PLANE + rem) * 8 + c8] = val;
            } else if (d < 128) {
                const int dd = d - 64, g = dd >> 3, c8 = dd & 7;
                kt[((b * GG + g) * PLANE + rem) * 8 + c8] = val;
            } else {
                const int dd = d - 128, g = dd >> 4, c16 = dd & 15;
                vt[((b * GG + g) * PLANE + rem) * 16 + c16] = val;
            }
        }
    }
}

// -------------------------------------------------------------------------
// Kernel 2: one block per (b, i, g).
//  s[j,w] = BN(qk)+BN(qr)+BN(kr); softmax over w per j; sv/sve over j; BN+add.
// -------------------------------------------------------------------------
__global__ __launch_bounds__(256) void attn_kernel(
    const float* __restrict__ qt, const float* __restrict__ kt, const float* __restrict__ vt,
    const float* __restrict__ q_rel, const float* __restrict__ k_rel, const float* __restrict__ v_rel,
    const float* __restrict__ g_qk, const float* __restrict__ b_qk,
    const float* __restrict__ g_qr, const float* __restrict__ b_qr,
    const float* __restrict__ g_kr, const float* __restrict__ b_kr,
    const float* __restrict__ g_sv, const float* __restrict__ b_sv,
    const float* __restrict__ g_sve, const float* __restrict__ b_sve,
    float* __restrict__ out)
{
    const int i = blockIdx.x;   // 56
    const int g = blockIdx.y;   // 8
    const int b = blockIdx.z;   // 32
    const int t = threadIdx.x;

    __shared__ float s[56][57];     // scores, then sim (in place)
    __shared__ float qi[56][8];     // q5[b,i,w,g,:]
    __shared__ float qe[56][8];     // q_emb[i,j,:]  = q_rel[i-j+55]
    __shared__ float ke[56][8];     // k_emb[j,i,:]  = k_rel[j-i+55]
    __shared__ float ve[56][16];    // v_emb[j,i,:]  = v_rel[j-i+55]

    const float inv = 1.0f / sqrtf(1.001f);
    const int bg = (b * GG + g) * PLANE;

    // ---- Phase A: stage LDS ----
    const float* qsrc = qt + (size_t)(bg + i * HH) * 8;
    for (int idx = t; idx < 448; idx += 256) {
        ((float*)qi)[idx] = qsrc[idx];
        ((float*)ke)[idx] = k_rel[(55 - i) * 8 + idx];
        ((float*)qe)[idx] = q_rel[(i + 55) * 8 - (idx & ~7) + (idx & 7)];
    }
    for (int idx = t; idx < 896; idx += 256)
        ((float*)ve)[idx] = v_rel[(55 - i) * 16 + idx];

    const float sqk = g_qk[g] * inv, bqk = b_qk[g];
    const float sqr = g_qr[g] * inv, bqr = b_qr[g];
    const float skr = g_kr[g] * inv, bkr = b_kr[g];
    __syncthreads();

    // ---- Phase B: scores s[j][w] ----
    for (int idx = t; idx < PLANE; idx += 256) {
        const int j = idx / 56;
        const int w = idx - j * 56;
        const float* kp = kt + (size_t)(bg + j * 56 + w) * 8;
        const float4 k0 = *(const float4*)(kp);
        const float4 k1 = *(const float4*)(kp + 4);
        const float4 q0 = *(const float4*)&qi[w][0];
        const float4 q1 = *(const float4*)&qi[w][4];
        const float4 e0 = *(const float4*)&qe[j][0];
        const float4 e1 = *(const float4*)&qe[j][4];
        const float4 f0 = *(const float4*)&ke[j][0];
        const float4 f1 = *(const float4*)&ke[j][4];

        float qk = q0.x*k0.x + q0.y*k0.y + q0.z*k0.z + q0.w*k0.w
                 + q1.x*k1.x + q1.y*k1.y + q1.z*k1.z + q1.w*k1.w;
        float qr = q0.x*e0.x + q0.y*e0.y + q0.z*e0.z + q0.w*e0.w
                 + q1.x*e1.x + q1.y*e1.y + q1.z*e1.z + q1.w*e1.w;
        float kr = k0.x*f0.x + k0.y*f0.y + k0.z*f0.z + k0.w*f0.w
                 + k1.x*f1.x + k1.y*f1.y + k1.z*f1.z + k1.w*f1.w;

        s[j][w] = fmaf(sqk, qk, bqk) + fmaf(sqr, qr, bqr) + fmaf(skr, kr, bkr);
    }
    __syncthreads();

    // ---- Phase C: softmax over w (per j row); wave wv handles 14 rows ----
    {
        const int wv = t >> 6, lane = t & 63;
        for (int jj = 0; jj < 14; ++jj) {
            const int j = wv * 14 + jj;
            const float v = (lane < 56) ? s[j][lane] : -3.0e38f;
            float m = v;
            #pragma unroll
            for (int off = 32; off >= 1; off >>= 1)
                m = fmaxf(m, __shfl_xor(m, off));
            const float e = (lane < 56) ? expf(v - m) : 0.f;
            float sum = e;
            #pragma unroll
            for (int off = 32; off >= 1; off >>= 1)
                sum += __shfl_xor(sum, off);
            if (lane < 56) s[j][lane] = e / sum;
        }
    }
    __syncthreads();

    // ---- Phase D: sv + sve, BN, store. Thread t<224: (w = t/4, c0 = (t%4)*4) ----
    if (t < 224) {
        const int w  = t >> 2;
        const int c0 = (t & 3) * 4;
        const float4* vrow = (const float4*)(vt + (size_t)bg * 16 + w * 16 + c0);
        float4 a1 = {0.f, 0.f, 0.f, 0.f};
        float4 a2 = {0.f, 0.f, 0.f, 0.f};
        #pragma unroll 4
        for (int j = 0; j < 56; ++j) {
            const float  p  = s[j][w];
            const float4 vv = vrow[j * 224];          // stride 896 floats
            const float4 ev = *(const float4*)&ve[j][c0];
            a1.x = fmaf(p, vv.x, a1.x); a1.y = fmaf(p, vv.y, a1.y);
            a1.z = fmaf(p, vv.z, a1.z); a1.w = fmaf(p, vv.w, a1.w);
            a2.x = fmaf(p, ev.x, a2.x); a2.y = fmaf(p, ev.y, a2.y);
            a2.z = fmaf(p, ev.z, a2.z); a2.w = fmaf(p, ev.w, a2.w);
        }
        const int ch = g * 16 + c0;
        const float4 gsv  = *(const float4*)(g_sv + ch);
        const float4 bsv  = *(const float4*)(b_sv + ch);
        const float4 gsve = *(const float4*)(g_sve + ch);
        const float4 bsve = *(const float4*)(b_sve + ch);
        float4 o;
        o.x = fmaf(gsv.x * inv, a1.x, bsv.x) + fmaf(gsve.x * inv, a2.x, bsve.x);
        o.y = fmaf(gsv.y * inv, a1.y, bsv.y) + fmaf(gsve.y * inv, a2.y, bsve.y);
        o.z = fmaf(gsv.z * inv, a1.z, bsv.z) + fmaf(gsve.z * inv, a2.z, bsve.z);
        o.w = fmaf(gsv.w * inv, a1.w, bsv.w) + fmaf(gsve.w * inv, a2.w, bsve.w);
        *(float4*)(out + ((size_t)(b * HH + i) * HH + w) * 128 + ch) = o;
    }
}

// -------------------------------------------------------------------------
extern "C" void kernel_launch(void* const* d_in, const int* in_sizes, int n_in,
                              void* d_out, int out_size, void* d_ws, size_t ws_size,
                              hipStream_t stream)
{
    const float* x     = (const float*)d_in[0];
    const float* w_q   = (const float*)d_in[1];
    const float* w_k   = (const float*)d_in[2];
    const float* w_v   = (const float*)d_in[3];
    const float* q_rel = (const float*)d_in[4];
    const float* k_rel = (const float*)d_in[5];
    const float* v_rel = (const float*)d_in[6];
    const float* g_q   = (const float*)d_in[7];
    const float* b_q   = (const float*)d_in[8];
    const float* g_k   = (const float*)d_in[9];
    const float* b_k   = (const float*)d_in[10];
    const float* g_v   = (const float*)d_in[11];
    const float* b_v   = (const float*)d_in[12];
    const float* g_qk  = (const float*)d_in[13];
    const float* b_qk  = (const float*)d_in[14];
    const float* g_qr  = (const float*)d_in[15];
    const float* b_qr  = (const float*)d_in[16];
    const float* g_kr  = (const float*)d_in[17];
    const float* b_kr  = (const float*)d_in[18];
    const float* g_sv  = (const float*)d_in[19];
    const float* b_sv  = (const float*)d_in[20];
    const float* g_sve = (const float*)d_in[21];
    const float* b_sve = (const float*)d_in[22];
    float* out = (float*)d_out;

    // workspace: qt/kt = 6,422,528 floats each, vt = 12,845,056 (102.8 MB total)
    const size_t qk_elems = (size_t)NB * GG * PLANE * 8;
    float* qt = (float*)d_ws;
    float* kt = qt + qk_elems;
    float* vt = kt + qk_elems;

    qkv_kernel<<<M_ROWS / 32, 256, 0, stream>>>(
        x, w_q, w_k, w_v, g_q, b_q, g_k, b_k, g_v, b_v, qt, kt, vt);

    attn_kernel<<<dim3(56, 8, 32), 256, 0, stream>>>(
        qt, kt, vt, q_rel, k_rel, v_rel,
        g_qk, b_qk, g_qr, b_qr, g_kr, b_kr, g_sv, b_sv, g_sve, b_sve, out);
}

// Round 3
// 358.024 us; speedup vs baseline: 1.3257x; 1.3257x over previous
//
#include <hip/hip_runtime.h>
#include <math.h>

// AxialAttention on MI355X — round 2.
// K1: f16 MFMA GEMM (16x16x32) for QKV projection + BN -> f16 workspace.
//     (bf16 failed absmax 0.75 > 0.5975; f16's 10-bit mantissa is 8x tighter.)
// K2: fused attention; q/k scores via v_dot2_f32_f16 (2 MAC/inst, fp32 accum).

static constexpr int NB    = 32;
static constexpr int HH    = 56;
static constexpr int CIN   = 128;
static constexpr int GG    = 8;
static constexpr int PLANE = HH * HH;          // 3136
static constexpr int M_ROWS = NB * PLANE;      // 100352

typedef _Float16 f16;
typedef _Float16 f16x2 __attribute__((ext_vector_type(2)));
typedef _Float16 f16x4 __attribute__((ext_vector_type(4)));
typedef _Float16 f16x8 __attribute__((ext_vector_type(8)));   // MFMA A/B frag (4 VGPR)
typedef float    f32x4 __attribute__((ext_vector_type(4)));   // MFMA C/D frag

// -------------------------------------------------------------------------
// Kernel 1: MFMA GEMM. A = x [100352,128] (fp32->f16), B = [wq|wk|wv] [128,256].
// Block tile 128(M) x 128(N), K=128 staged fully. Grid (784, 2): y=0 -> q|k, y=1 -> v.
// 4 waves, each 64x64 wave tile = 4x4 MFMA tiles of 16x16x32.
// LDS rows padded to 136 halves (272 B — 16B-aligned; frag reads conflict-free).
// -------------------------------------------------------------------------
__global__ __launch_bounds__(256, 2) void qkv_mfma_kernel(
    const float* __restrict__ x,
    const float* __restrict__ wq, const float* __restrict__ wk, const float* __restrict__ wv,
    const float* __restrict__ gq, const float* __restrict__ bq,
    const float* __restrict__ gk, const float* __restrict__ bk,
    const float* __restrict__ gv, const float* __restrict__ bv,
    f16* __restrict__ qt, f16* __restrict__ kt, f16* __restrict__ vt)
{
    __shared__ f16 lds_a[128 * 136];   // A[m][k]
    __shared__ f16 lds_b[128 * 136];   // Bt[n][k] = W[k][n]

    const int t  = threadIdx.x;
    const int m0 = blockIdx.x * 128;
    const int nh = blockIdx.y;         // 0: cols 0..127 (q|k), 1: cols 128..255 (v)

    // ---- stage A (coalesced float4, cvt to f16) ----
    {
        const float4* xsrc = (const float4*)(x + (size_t)m0 * CIN);
        #pragma unroll
        for (int it = 0; it < 16; ++it) {
            const int f = it * 256 + t;          // float4-unit index; 32 per row
            const int r = f >> 5, c = f & 31;
            const float4 v = xsrc[f];
            f16x4 p; p.x = (f16)v.x; p.y = (f16)v.y; p.z = (f16)v.z; p.w = (f16)v.w;
            *(f16x4*)&lds_a[r * 136 + c * 4] = p;
        }
    }

    // ---- stage B transposed (coalesced over n per scalar read) ----
    {
        const int n     = (t & 63) + ((t >> 6) & 1) * 64;  // 0..127
        const int khalf = (t >> 7) * 64;                   // 0 or 64
        const int ng    = nh * 128 + n;
        const float* wp; int stride;
        if (ng < 64)       { wp = wq + ng;         stride = 64;  }
        else if (ng < 128) { wp = wk + (ng - 64);  stride = 64;  }
        else               { wp = wv + (ng - 128); stride = 128; }
        #pragma unroll
        for (int it = 0; it < 16; ++it) {
            const int kb = khalf + it * 4;
            f16x4 p;
            p.x = (f16)wp[(size_t)(kb + 0) * stride];
            p.y = (f16)wp[(size_t)(kb + 1) * stride];
            p.z = (f16)wp[(size_t)(kb + 2) * stride];
            p.w = (f16)wp[(size_t)(kb + 3) * stride];
            *(f16x4*)&lds_b[n * 136 + kb] = p;
        }
    }
    __syncthreads();

    // ---- K-loop ----
    const int lane = t & 63;
    const int wid  = t >> 6;
    const int wm0  = (wid >> 1) * 64;
    const int wn0  = (wid & 1) * 64;
    const int ra   = lane & 15;        // A row / B row / C col
    const int qd   = lane >> 4;        // quad: k = qd*8+j ; C row = qd*4+reg

    f32x4 acc[4][4];
    #pragma unroll
    for (int mt = 0; mt < 4; ++mt)
        #pragma unroll
        for (int nt = 0; nt < 4; ++nt)
            acc[mt][nt] = (f32x4){0.f, 0.f, 0.f, 0.f};

    #pragma unroll
    for (int ks = 0; ks < 4; ++ks) {
        f16x8 af[4], bfr[4];
        #pragma unroll
        for (int mt = 0; mt < 4; ++mt)
            af[mt] = *(const f16x8*)&lds_a[(wm0 + mt * 16 + ra) * 136 + ks * 32 + qd * 8];
        #pragma unroll
        for (int nt = 0; nt < 4; ++nt)
            bfr[nt] = *(const f16x8*)&lds_b[(wn0 + nt * 16 + ra) * 136 + ks * 32 + qd * 8];
        #pragma unroll
        for (int mt = 0; mt < 4; ++mt)
            #pragma unroll
            for (int nt = 0; nt < 4; ++nt)
                acc[mt][nt] = __builtin_amdgcn_mfma_f32_16x16x32_f16(
                    af[mt], bfr[nt], acc[mt][nt], 0, 0, 0);
    }

    // ---- epilogue: BN + permuted f16 store ----
    const float inv = 1.0f / sqrtf(1.001f);
    #pragma unroll
    for (int nt = 0; nt < 4; ++nt) {
        const int d = nh * 128 + wn0 + nt * 16 + ra;   // 0..255
        float scale, shift;
        if (d < 64)       { scale = gq[d] * inv;        shift = bq[d]; }
        else if (d < 128) { scale = gk[d - 64] * inv;   shift = bk[d - 64]; }
        else              { scale = gv[d - 128] * inv;  shift = bv[d - 128]; }
        #pragma unroll
        for (int mt = 0; mt < 4; ++mt) {
            #pragma unroll
            for (int rg = 0; rg < 4; ++rg) {
                const int m   = m0 + wm0 + mt * 16 + qd * 4 + rg;
                const int b   = m / PLANE;
                const int rem = m - b * PLANE;
                const f16 val = (f16)fmaf(acc[mt][nt][rg], scale, shift);
                if (d < 64) {
                    const int g = d >> 3, c = d & 7;
                    qt[((size_t)(b * GG + g) * PLANE + rem) * 8 + c] = val;
                } else if (d < 128) {
                    const int dd = d - 64, g = dd >> 3, c = dd & 7;
                    kt[((size_t)(b * GG + g) * PLANE + rem) * 8 + c] = val;
                } else {
                    const int dd = d - 128, g = dd >> 4, c = dd & 15;
                    vt[((size_t)(b * GG + g) * PLANE + rem) * 16 + c] = val;
                }
            }
        }
    }
}

// -------------------------------------------------------------------------
// Kernel 2: one block per (b, i, g). q/k/v are f16; scores via fdot2 (fp32 acc).
// -------------------------------------------------------------------------
__global__ __launch_bounds__(256) void attn_kernel(
    const f16* __restrict__ qt, const f16* __restrict__ kt, const f16* __restrict__ vt,
    const float* __restrict__ q_rel, const float* __restrict__ k_rel, const float* __restrict__ v_rel,
    const float* __restrict__ g_qk, const float* __restrict__ b_qk,
    const float* __restrict__ g_qr, const float* __restrict__ b_qr,
    const float* __restrict__ g_kr, const float* __restrict__ b_kr,
    const float* __restrict__ g_sv, const float* __restrict__ b_sv,
    const float* __restrict__ g_sve, const float* __restrict__ b_sve,
    float* __restrict__ out)
{
    const int i = blockIdx.x;   // 56
    const int g = blockIdx.y;   // 8
    const int b = blockIdx.z;   // 32
    const int t = threadIdx.x;

    __shared__ float s[56][57];     // scores, then sim (in place)
    __shared__ f16   qi[56][8];     // q5[b,i,w,g,:]
    __shared__ f16   qe[56][8];     // q_emb[i,j,:]  = q_rel[i-j+55]
    __shared__ f16   ke[56][8];     // k_emb[j,i,:]  = k_rel[j-i+55]
    __shared__ float ve[56][16];    // v_emb[j,i,:]  = v_rel[j-i+55]

    const float inv = 1.0f / sqrtf(1.001f);
    const int bg = (b * GG + g) * PLANE;

    // ---- Phase A: stage LDS ----
    const f16* qsrc = qt + (size_t)(bg + i * HH) * 8;
    for (int idx = t; idx < 448; idx += 256) {
        ((f16*)qi)[idx] = qsrc[idx];
        ((f16*)ke)[idx] = (f16)k_rel[(55 - i) * 8 + idx];
        ((f16*)qe)[idx] = (f16)q_rel[(i + 55) * 8 - (idx & ~7) + (idx & 7)];
    }
    for (int idx = t; idx < 896; idx += 256)
        ((float*)ve)[idx] = v_rel[(55 - i) * 16 + idx];

    const float sqk = g_qk[g] * inv, bqk = b_qk[g];
    const float sqr = g_qr[g] * inv, bqr = b_qr[g];
    const float skr = g_kr[g] * inv, bkr = b_kr[g];
    __syncthreads();

    // ---- Phase B: scores s[j][w] via v_dot2_f32_f16 ----
    for (int idx = t; idx < PLANE; idx += 256) {
        const int j = idx / 56;
        const int w = idx - j * 56;
        const f16x2* kp = (const f16x2*)(kt + (size_t)(bg + j * 56 + w) * 8);
        const f16x2* qp = (const f16x2*)&qi[w][0];
        const f16x2* ep = (const f16x2*)&qe[j][0];
        const f16x2* fp = (const f16x2*)&ke[j][0];

        float qk = 0.f, qr = 0.f, kr = 0.f;
        #pragma unroll
        for (int c = 0; c < 4; ++c) {
            const f16x2 kk = kp[c];
            const f16x2 qq = qp[c];
            qk = __builtin_amdgcn_fdot2(qq, kk,    qk, false);
            qr = __builtin_amdgcn_fdot2(qq, ep[c], qr, false);
            kr = __builtin_amdgcn_fdot2(kk, fp[c], kr, false);
        }
        s[j][w] = fmaf(sqk, qk, bqk) + fmaf(sqr, qr, bqr) + fmaf(skr, kr, bkr);
    }
    __syncthreads();

    // ---- Phase C: softmax over w (per j row); wave wv handles 14 rows ----
    {
        const int wv = t >> 6, lane = t & 63;
        for (int jj = 0; jj < 14; ++jj) {
            const int j = wv * 14 + jj;
            const float v = (lane < 56) ? s[j][lane] : -3.0e38f;
            float m = v;
            #pragma unroll
            for (int off = 32; off >= 1; off >>= 1)
                m = fmaxf(m, __shfl_xor(m, off));
            const float e = (lane < 56) ? expf(v - m) : 0.f;
            float sum = e;
            #pragma unroll
            for (int off = 32; off >= 1; off >>= 1)
                sum += __shfl_xor(sum, off);
            if (lane < 56) s[j][lane] = e / sum;
        }
    }
    __syncthreads();

    // ---- Phase D: sv + sve, BN, store. Thread t<224: (w = t/4, c0 = (t%4)*4) ----
    if (t < 224) {
        const int w  = t >> 2;
        const int c0 = (t & 3) * 4;
        const f16* vrow = vt + (size_t)bg * 16 + w * 16 + c0;
        float4 a1 = {0.f, 0.f, 0.f, 0.f};
        float4 a2 = {0.f, 0.f, 0.f, 0.f};
        #pragma unroll 4
        for (int j = 0; j < 56; ++j) {
            const float  p   = s[j][w];
            const f16x4  vrw = *(const f16x4*)(vrow + (size_t)j * 896);
            const float4 ev  = *(const float4*)&ve[j][c0];
            a1.x = fmaf(p, (float)vrw.x, a1.x); a1.y = fmaf(p, (float)vrw.y, a1.y);
            a1.z = fmaf(p, (float)vrw.z, a1.z); a1.w = fmaf(p, (float)vrw.w, a1.w);
            a2.x = fmaf(p, ev.x, a2.x); a2.y = fmaf(p, ev.y, a2.y);
            a2.z = fmaf(p, ev.z, a2.z); a2.w = fmaf(p, ev.w, a2.w);
        }
        const int ch = g * 16 + c0;
        const float4 gsv  = *(const float4*)(g_sv + ch);
        const float4 bsv  = *(const float4*)(b_sv + ch);
        const float4 gsve = *(const float4*)(g_sve + ch);
        const float4 bsve = *(const float4*)(b_sve + ch);
        float4 o;
        o.x = fmaf(gsv.x * inv, a1.x, bsv.x) + fmaf(gsve.x * inv, a2.x, bsve.x);
        o.y = fmaf(gsv.y * inv, a1.y, bsv.y) + fmaf(gsve.y * inv, a2.y, bsve.y);
        o.z = fmaf(gsv.z * inv, a1.z, bsv.z) + fmaf(gsve.z * inv, a2.z, bsve.z);
        o.w = fmaf(gsv.w * inv, a1.w, bsv.w) + fmaf(gsve.w * inv, a2.w, bsve.w);
        *(float4*)(out + ((size_t)(b * HH + i) * HH + w) * 128 + ch) = o;
    }
}

// -------------------------------------------------------------------------
extern "C" void kernel_launch(void* const* d_in, const int* in_sizes, int n_in,
                              void* d_out, int out_size, void* d_ws, size_t ws_size,
                              hipStream_t stream)
{
    const float* x     = (const float*)d_in[0];
    const float* w_q   = (const float*)d_in[1];
    const float* w_k   = (const float*)d_in[2];
    const float* w_v   = (const float*)d_in[3];
    const float* q_rel = (const float*)d_in[4];
    const float* k_rel = (const float*)d_in[5];
    const float* v_rel = (const float*)d_in[6];
    const float* g_q   = (const float*)d_in[7];
    const float* b_q   = (const float*)d_in[8];
    const float* g_k   = (const float*)d_in[9];
    const float* b_k   = (const float*)d_in[10];
    const float* g_v   = (const float*)d_in[11];
    const float* b_v   = (const float*)d_in[12];
    const float* g_qk  = (const float*)d_in[13];
    const float* b_qk  = (const float*)d_in[14];
    const float* g_qr  = (const float*)d_in[15];
    const float* b_qr  = (const float*)d_in[16];
    const float* g_kr  = (const float*)d_in[17];
    const float* b_kr  = (const float*)d_in[18];
    const float* g_sv  = (const float*)d_in[19];
    const float* b_sv  = (const float*)d_in[20];
    const float* g_sve = (const float*)d_in[21];
    const float* b_sve = (const float*)d_in[22];
    float* out = (float*)d_out;

    // workspace (f16): qt/kt = 6,422,528 halves each, vt = 12,845,056 (51.4 MB)
    const size_t qk_elems = (size_t)NB * GG * PLANE * 8;
    f16* qt = (f16*)d_ws;
    f16* kt = qt + qk_elems;
    f16* vt = kt + qk_elems;

    qkv_mfma_kernel<<<dim3(M_ROWS / 128, 2), 256, 0, stream>>>(
        x, w_q, w_k, w_v, g_q, b_q, g_k, b_k, g_v, b_v, qt, kt, vt);

    attn_kernel<<<dim3(56, 8, 32), 256, 0, stream>>>(
        qt, kt, vt, q_rel, k_rel, v_rel,
        g_qk, b_qk, g_qr, b_qr, g_kr, b_kr, g_sv, b_sv, g_sve, b_sve, out);
}

// Round 5
// 304.425 us; speedup vs baseline: 1.5591x; 1.1761x over previous
//
#include <hip/hip_runtime.h>
#include <math.h>

// AxialAttention on MI355X — round 4.
// = round 3 with the softmax fixed: per-row MAX reduction restored (the
//   const-shift exp(s-20) overflowed: per-group logit std reaches ~38 due to
//   BN gammas, so s>108 at ~3 sigma -> e=inf -> p=NaN).
// prep: W -> f16 [d][k] for coalesced K1 staging.
// K1: f16 MFMA GEMM, M-tile 112 (aligned j-pairs), LDS-transpose epilogue,
//     all-coalesced 16B stores; v written j-pair-interleaved (vt2) for K2.
// K2: fused attention; Phase B+softmax fused (max+sum butterflies);
//     Phase D via v_dot2_f32_f16 over j-pairs.

typedef _Float16 f16;
typedef _Float16 f16x2 __attribute__((ext_vector_type(2)));
typedef _Float16 f16x4 __attribute__((ext_vector_type(4)));
typedef _Float16 f16x8 __attribute__((ext_vector_type(8)));
typedef float    f32x4 __attribute__((ext_vector_type(4)));
typedef unsigned int u32;
typedef unsigned int u32x2 __attribute__((ext_vector_type(2)));

static constexpr int NB    = 32;
static constexpr int HH    = 56;
static constexpr int CIN   = 128;
static constexpr int GG    = 8;
static constexpr int PLANE = HH * HH;     // 3136
static constexpr int MT    = 112;         // K1 M-tile (2 j-rows x 56 w)
static constexpr int NBLK  = 28;          // 3136 / 112

// -------------------------------------------------------------------------
// prep: Wt[d][k] f16, d in [0,256): 0-63 <- wq, 64-127 <- wk, 128-255 <- wv
// -------------------------------------------------------------------------
__global__ __launch_bounds__(256) void prep_kernel(
    const float* __restrict__ wq, const float* __restrict__ wk,
    const float* __restrict__ wv, f16* __restrict__ wt)
{
    const int id = blockIdx.x * 256 + threadIdx.x;   // 4096 total
    const int d = id >> 4, kc = id & 15;
    const float* src; int stride, dl;
    if (d < 64)       { src = wq; stride = 64;  dl = d; }
    else if (d < 128) { src = wk; stride = 64;  dl = d - 64; }
    else              { src = wv; stride = 128; dl = d - 128; }
    f16x8 v;
    #pragma unroll
    for (int kk = 0; kk < 8; ++kk)
        v[kk] = (f16)src[(kc * 8 + kk) * stride + dl];
    *(f16x8*)&wt[d * 128 + kc * 8] = v;
}

// -------------------------------------------------------------------------
// K1: block tile 112(M) x 128(N), K=128. Grid (896, 2): y=0 -> q|k, y=1 -> v.
// 4 waves, each 112m x 32n (7x2 MFMA tiles of 16x16x32).
// Epilogue: BN -> f16 -> LDS[m][d] transpose -> coalesced 16B stores.
// -------------------------------------------------------------------------
__global__ __launch_bounds__(256, 2) void qkv_kernel(
    const float* __restrict__ x, const f16* __restrict__ wt,
    const float* __restrict__ gq, const float* __restrict__ bq,
    const float* __restrict__ gk, const float* __restrict__ bk,
    const float* __restrict__ gv, const float* __restrict__ bv,
    f16* __restrict__ qt, f16* __restrict__ kt, f16* __restrict__ vt2)
{
    __shared__ f16 lds_a[MT * 136];     // A[m][k], later reused as C[m][d]
    __shared__ f16 lds_b[128 * 136];    // Bt[n][k]

    const int t    = threadIdx.x;
    const int nh   = blockIdx.y;
    const int b    = blockIdx.x / NBLK;
    const int B28  = blockIdx.x - b * NBLK;
    const int rem0 = B28 * MT;
    const size_t m0 = (size_t)b * PLANE + rem0;

    // ---- stage A: 112x128 f32 -> f16, coalesced float4 ----
    {
        const float4* xs = (const float4*)(x + m0 * CIN);
        #pragma unroll
        for (int it = 0; it < 14; ++it) {
            const int f = it * 256 + t;          // 3584 float4
            const int r = f >> 5, c = f & 31;
            const float4 v = xs[f];
            f16x4 p; p.x = (f16)v.x; p.y = (f16)v.y; p.z = (f16)v.z; p.w = (f16)v.w;
            *(f16x4*)&lds_a[r * 136 + c * 4] = p;
        }
    }
    // ---- stage B: pre-converted Wt, coalesced 16B ----
    #pragma unroll
    for (int it = 0; it < 8; ++it) {
        const int f = it * 256 + t;              // 2048 chunks
        const int n = f >> 4, kc = f & 15;
        *(f16x8*)&lds_b[n * 136 + kc * 8] =
            *(const f16x8*)&wt[(size_t)(nh * 128 + n) * 128 + kc * 8];
    }
    __syncthreads();

    const int lane = t & 63, wid = t >> 6;
    const int wn0 = wid * 32;
    const int ra = lane & 15, qd = lane >> 4;

    f32x4 acc[7][2];
    #pragma unroll
    for (int mt = 0; mt < 7; ++mt)
        #pragma unroll
        for (int nt = 0; nt < 2; ++nt)
            acc[mt][nt] = (f32x4){0.f, 0.f, 0.f, 0.f};

    #pragma unroll
    for (int ks = 0; ks < 4; ++ks) {
        f16x8 af[7], bf[2];
        #pragma unroll
        for (int mt = 0; mt < 7; ++mt)
            af[mt] = *(const f16x8*)&lds_a[(mt * 16 + ra) * 136 + ks * 32 + qd * 8];
        #pragma unroll
        for (int nt = 0; nt < 2; ++nt)
            bf[nt] = *(const f16x8*)&lds_b[(wn0 + nt * 16 + ra) * 136 + ks * 32 + qd * 8];
        #pragma unroll
        for (int mt = 0; mt < 7; ++mt)
            #pragma unroll
            for (int nt = 0; nt < 2; ++nt)
                acc[mt][nt] = __builtin_amdgcn_mfma_f32_16x16x32_f16(
                    af[mt], bf[nt], acc[mt][nt], 0, 0, 0);
    }
    __syncthreads();

    // ---- BN + f16, transpose via LDS (reuse lds_a as C[m][d]) ----
    f16* lds_c = lds_a;
    const float inv = 1.0f / sqrtf(1.001f);
    #pragma unroll
    for (int nt = 0; nt < 2; ++nt) {
        const int d  = wn0 + nt * 16 + ra;       // block-local col 0..127
        const int dg = nh * 128 + d;             // global col 0..255
        float scale, shift;
        if (dg < 64)       { scale = gq[dg] * inv;        shift = bq[dg]; }
        else if (dg < 128) { scale = gk[dg - 64] * inv;   shift = bk[dg - 64]; }
        else               { scale = gv[dg - 128] * inv;  shift = bv[dg - 128]; }
        #pragma unroll
        for (int mt = 0; mt < 7; ++mt)
            #pragma unroll
            for (int rg = 0; rg < 4; ++rg) {
                const int m = mt * 16 + qd * 4 + rg;
                lds_c[m * 136 + d] = (f16)fmaf(acc[mt][nt][rg], scale, shift);
            }
    }
    __syncthreads();

    if (nh == 0) {
        // q/k: chunk = (gslot 0..15, rem 0..111): 16B row stores, coalesced
        const int rl = t & 31, gs2 = t >> 5;
        #pragma unroll
        for (int it = 0; it < 4; ++it) {
            const int rem = it * 32 + rl;
            if (rem < MT) {
                #pragma unroll
                for (int half = 0; half < 2; ++half) {
                    const int gslot = half * 8 + gs2;
                    const f16x8 v = *(const f16x8*)&lds_c[rem * 136 + gslot * 8];
                    f16* dst = (gslot < 8) ? qt : kt;
                    const int g = gslot & 7;
                    *(f16x8*)&dst[((size_t)(b * GG + g) * PLANE + rem0 + rem) * 8] = v;
                }
            }
        }
    } else {
        // v -> vt2[bg][J=B28][w][c][jbit]: interleave rows w and w+56
        const int cq = t & 3, w8 = (t >> 2) & 7, g = t >> 5;
        #pragma unroll
        for (int it = 0; it < 7; ++it) {
            const int w = it * 8 + w8;
            const int doff = g * 16 + cq * 4;
            const u32x2 a  = *(const u32x2*)&lds_c[w * 136 + doff];         // j0: c0..c3
            const u32x2 bb = *(const u32x2*)&lds_c[(56 + w) * 136 + doff];  // j1: c0..c3
            uint4 o;
            o.x = __builtin_amdgcn_perm(a.x, bb.x, 0x01000504u);  // c0j0 c0j1
            o.y = __builtin_amdgcn_perm(a.x, bb.x, 0x03020706u);  // c1j0 c1j1
            o.z = __builtin_amdgcn_perm(a.y, bb.y, 0x01000504u);  // c2j0 c2j1
            o.w = __builtin_amdgcn_perm(a.y, bb.y, 0x03020706u);  // c3j0 c3j1
            const size_t base =
                (((size_t)(b * GG + g) * NBLK + B28) * HH + w) * 32 + cq * 8;
            *(uint4*)&vt2[base] = o;
        }
    }
}

// -------------------------------------------------------------------------
// K2: one block per (b, i, g).
// -------------------------------------------------------------------------
__global__ __launch_bounds__(256) void attn_kernel(
    const f16* __restrict__ qt, const f16* __restrict__ kt, const f16* __restrict__ vt2,
    const float* __restrict__ q_rel, const float* __restrict__ k_rel, const float* __restrict__ v_rel,
    const float* __restrict__ g_qk, const float* __restrict__ b_qk,
    const float* __restrict__ g_qr, const float* __restrict__ b_qr,
    const float* __restrict__ g_kr, const float* __restrict__ b_kr,
    const float* __restrict__ g_sv, const float* __restrict__ b_sv,
    const float* __restrict__ g_sve, const float* __restrict__ b_sve,
    float* __restrict__ out)
{
    const int i = blockIdx.x;   // 56
    const int g = blockIdx.y;   // 8
    const int b = blockIdx.z;   // 32
    const int t = threadIdx.x;

    __shared__ f16 qi[56 * 8];      // q5[b,i,w,g,:]
    __shared__ f16 qe[56 * 8];      // q_emb[i,j,:] = q_rel[i-j+55]
    __shared__ f16 ke[56 * 8];      // k_emb[j,i,:] = k_rel[j-i+55]
    __shared__ f16 ve2[28 * 32];    // v_emb j-pair-interleaved [J][c][jbit]
    __shared__ f16 s16[56 * 58];    // normalized sim, transposed [w][j], pad 58

    const float inv = 1.0f / sqrtf(1.001f);
    const int bg = (b * GG + g) * PLANE;

    // ---- Phase A: stage LDS ----
    if (t < 56)
        *(f16x8*)&qi[t * 8] = *(const f16x8*)&qt[(size_t)(bg + i * HH + t) * 8];
    for (int idx = t; idx < 448; idx += 256) {
        const int j = idx >> 3, c = idx & 7;
        qe[idx] = (f16)q_rel[(i - j + 55) * 8 + c];
        ke[idx] = (f16)k_rel[(j - i + 55) * 8 + c];
    }
    for (int idx = t; idx < 896; idx += 256) {
        const int J = idx >> 5, r = idx & 31, c = r >> 1, jb = r & 1;
        ve2[idx] = (f16)v_rel[(2 * J + jb - i + 55) * 16 + c];
    }
    const float sqk = g_qk[g] * inv, bqk = b_qk[g];
    const float sqr = g_qr[g] * inv, bqr = b_qr[g];
    const float skr = g_kr[g] * inv, bkr = b_kr[g];
    __syncthreads();

    // ---- Phase B+C fused: wave = j-rows, lanes = w; max+sum butterflies ----
    {
        const int wv = t >> 6, lane = t & 63;
        const int wc = (lane < 56) ? lane : 55;
        const f16x8 qv = *(const f16x8*)&qi[wc * 8];
        for (int jj = 0; jj < 14; ++jj) {
            const int j = wv * 14 + jj;
            const f16x8 kv = *(const f16x8*)&kt[(size_t)(bg + j * HH + wc) * 8];
            const f16x8 ev = *(const f16x8*)&qe[j * 8];   // LDS broadcast
            const f16x8 fv = *(const f16x8*)&ke[j * 8];   // LDS broadcast
            float qk = 0.f, qr = 0.f, kr = 0.f;
            #pragma unroll
            for (int c = 0; c < 4; ++c) {
                const f16x2 kk = ((const f16x2*)&kv)[c];
                const f16x2 qq = ((const f16x2*)&qv)[c];
                qk = __builtin_amdgcn_fdot2(qq, kk, qk, false);
                qr = __builtin_amdgcn_fdot2(qq, ((const f16x2*)&ev)[c], qr, false);
                kr = __builtin_amdgcn_fdot2(kk, ((const f16x2*)&fv)[c], kr, false);
            }
            const float s = fmaf(sqk, qk, bqk) + fmaf(sqr, qr, bqr) + fmaf(skr, kr, bkr);
            float mx = (lane < 56) ? s : -3.0e38f;
            #pragma unroll
            for (int off = 1; off <= 32; off <<= 1)
                mx = fmaxf(mx, __shfl_xor(mx, off));
            float e = (lane < 56) ? __expf(s - mx) : 0.f;   // e in (0,1]
            float sum = e;
            #pragma unroll
            for (int off = 1; off <= 32; off <<= 1)
                sum += __shfl_xor(sum, off);                // sum in [1,56]
            const float p = e * __builtin_amdgcn_rcpf(sum);
            if (lane < 56) s16[lane * 58 + j] = (f16)p;
        }
    }
    __syncthreads();

    // ---- Phase D: sv + sve via fdot2 over j-pairs. t<224: (w=t/4, cq=t%4) ----
    if (t < 224) {
        const int w = t >> 2, cq = t & 3;
        const f16* vp = vt2 + ((size_t)(b * GG + g) * NBLK * HH + w) * 32 + cq * 8;
        float sv[4] = {0.f, 0.f, 0.f, 0.f};
        float se[4] = {0.f, 0.f, 0.f, 0.f};
        #pragma unroll 4
        for (int J = 0; J < 28; ++J) {
            const f16x2 pp = *(const f16x2*)&s16[w * 58 + 2 * J];
            const f16x8 vl = *(const f16x8*)(vp + (size_t)J * (HH * 32));
            const f16x8 el = *(const f16x8*)&ve2[J * 32 + cq * 8];
            #pragma unroll
            for (int c = 0; c < 4; ++c) {
                sv[c] = __builtin_amdgcn_fdot2(pp, ((const f16x2*)&vl)[c], sv[c], false);
                se[c] = __builtin_amdgcn_fdot2(pp, ((const f16x2*)&el)[c], se[c], false);
            }
        }
        const int ch = g * 16 + cq * 4;
        const float4 gsv  = *(const float4*)(g_sv + ch);
        const float4 bsv  = *(const float4*)(b_sv + ch);
        const float4 gsve = *(const float4*)(g_sve + ch);
        const float4 bsve = *(const float4*)(b_sve + ch);
        float4 o;
        o.x = fmaf(gsv.x * inv, sv[0], bsv.x) + fmaf(gsve.x * inv, se[0], bsve.x);
        o.y = fmaf(gsv.y * inv, sv[1], bsv.y) + fmaf(gsve.y * inv, se[1], bsve.y);
        o.z = fmaf(gsv.z * inv, sv[2], bsv.z) + fmaf(gsve.z * inv, se[2], bsve.z);
        o.w = fmaf(gsv.w * inv, sv[3], bsv.w) + fmaf(gsve.w * inv, se[3], bsve.w);
        *(float4*)(out + ((size_t)(b * HH + i) * HH + w) * 128 + ch) = o;
    }
}

// -------------------------------------------------------------------------
extern "C" void kernel_launch(void* const* d_in, const int* in_sizes, int n_in,
                              void* d_out, int out_size, void* d_ws, size_t ws_size,
                              hipStream_t stream)
{
    const float* x     = (const float*)d_in[0];
    const float* w_q   = (const float*)d_in[1];
    const float* w_k   = (const float*)d_in[2];
    const float* w_v   = (const float*)d_in[3];
    const float* q_rel = (const float*)d_in[4];
    const float* k_rel = (const float*)d_in[5];
    const float* v_rel = (const float*)d_in[6];
    const float* g_q   = (const float*)d_in[7];
    const float* b_q   = (const float*)d_in[8];
    const float* g_k   = (const float*)d_in[9];
    const float* b_k   = (const float*)d_in[10];
    const float* g_v   = (const float*)d_in[11];
    const float* b_v   = (const float*)d_in[12];
    const float* g_qk  = (const float*)d_in[13];
    const float* b_qk  = (const float*)d_in[14];
    const float* g_qr  = (const float*)d_in[15];
    const float* b_qr  = (const float*)d_in[16];
    const float* g_kr  = (const float*)d_in[17];
    const float* b_kr  = (const float*)d_in[18];
    const float* g_sv  = (const float*)d_in[19];
    const float* b_sv  = (const float*)d_in[20];
    const float* g_sve = (const float*)d_in[21];
    const float* b_sve = (const float*)d_in[22];
    float* out = (float*)d_out;

    // workspace (f16): wt 32768 | qt/kt 6,422,528 each | vt2 12,845,056 (~51.5 MB)
    f16* wt  = (f16*)d_ws;
    f16* qt  = wt + 32768;
    f16* kt  = qt + (size_t)NB * GG * PLANE * 8;
    f16* vt2 = kt + (size_t)NB * GG * PLANE * 8;

    prep_kernel<<<16, 256, 0, stream>>>(w_q, w_k, w_v, wt);

    qkv_kernel<<<dim3((NB * PLANE) / MT, 2), 256, 0, stream>>>(
        x, wt, g_q, b_q, g_k, b_k, g_v, b_v, qt, kt, vt2);

    attn_kernel<<<dim3(56, 8, 32), 256, 0, stream>>>(
        qt, kt, vt2, q_rel, k_rel, v_rel,
        g_qk, b_qk, g_qr, b_qr, g_kr, b_kr, g_sv, b_sv, g_sve, b_sve, out);
}

// Round 6
// 254.533 us; speedup vs baseline: 1.8648x; 1.1960x over previous
//
#include <hip/hip_runtime.h>
#include <math.h>

// AxialAttention on MI355X — round 5.
// K1/prep unchanged from round 4 (residual ~128us is hypothesized fixed
// harness overhead, not K1 — this round tests that by only touching attn).
// K2: Phase B writes raw fp32 scores (no cross-lane); Phase C = quad-local
// softmax (2+2 DPP shfl instead of 12 wide shfl per row); Phase D reads p
// in f16x4 pairs.

typedef _Float16 f16;
typedef _Float16 f16x2 __attribute__((ext_vector_type(2)));
typedef _Float16 f16x4 __attribute__((ext_vector_type(4)));
typedef _Float16 f16x8 __attribute__((ext_vector_type(8)));
typedef float    f32x4 __attribute__((ext_vector_type(4)));
typedef unsigned int u32;
typedef unsigned int u32x2 __attribute__((ext_vector_type(2)));

static constexpr int NB    = 32;
static constexpr int HH    = 56;
static constexpr int CIN   = 128;
static constexpr int GG    = 8;
static constexpr int PLANE = HH * HH;     // 3136
static constexpr int MT    = 112;         // K1 M-tile (2 j-rows x 56 w)
static constexpr int NBLK  = 28;          // 3136 / 112

// -------------------------------------------------------------------------
// prep: Wt[d][k] f16, d in [0,256): 0-63 <- wq, 64-127 <- wk, 128-255 <- wv
// -------------------------------------------------------------------------
__global__ __launch_bounds__(256) void prep_kernel(
    const float* __restrict__ wq, const float* __restrict__ wk,
    const float* __restrict__ wv, f16* __restrict__ wt)
{
    const int id = blockIdx.x * 256 + threadIdx.x;   // 4096 total
    const int d = id >> 4, kc = id & 15;
    const float* src; int stride, dl;
    if (d < 64)       { src = wq; stride = 64;  dl = d; }
    else if (d < 128) { src = wk; stride = 64;  dl = d - 64; }
    else              { src = wv; stride = 128; dl = d - 128; }
    f16x8 v;
    #pragma unroll
    for (int kk = 0; kk < 8; ++kk)
        v[kk] = (f16)src[(kc * 8 + kk) * stride + dl];
    *(f16x8*)&wt[d * 128 + kc * 8] = v;
}

// -------------------------------------------------------------------------
// K1: block tile 112(M) x 128(N), K=128. Grid (896, 2): y=0 -> q|k, y=1 -> v.
// -------------------------------------------------------------------------
__global__ __launch_bounds__(256, 2) void qkv_kernel(
    const float* __restrict__ x, const f16* __restrict__ wt,
    const float* __restrict__ gq, const float* __restrict__ bq,
    const float* __restrict__ gk, const float* __restrict__ bk,
    const float* __restrict__ gv, const float* __restrict__ bv,
    f16* __restrict__ qt, f16* __restrict__ kt, f16* __restrict__ vt2)
{
    __shared__ f16 lds_a[MT * 136];     // A[m][k], later reused as C[m][d]
    __shared__ f16 lds_b[128 * 136];    // Bt[n][k]

    const int t    = threadIdx.x;
    const int nh   = blockIdx.y;
    const int b    = blockIdx.x / NBLK;
    const int B28  = blockIdx.x - b * NBLK;
    const int rem0 = B28 * MT;
    const size_t m0 = (size_t)b * PLANE + rem0;

    // ---- stage A: 112x128 f32 -> f16, coalesced float4 ----
    {
        const float4* xs = (const float4*)(x + m0 * CIN);
        #pragma unroll
        for (int it = 0; it < 14; ++it) {
            const int f = it * 256 + t;          // 3584 float4
            const int r = f >> 5, c = f & 31;
            const float4 v = xs[f];
            f16x4 p; p.x = (f16)v.x; p.y = (f16)v.y; p.z = (f16)v.z; p.w = (f16)v.w;
            *(f16x4*)&lds_a[r * 136 + c * 4] = p;
        }
    }
    // ---- stage B: pre-converted Wt, coalesced 16B ----
    #pragma unroll
    for (int it = 0; it < 8; ++it) {
        const int f = it * 256 + t;              // 2048 chunks
        const int n = f >> 4, kc = f & 15;
        *(f16x8*)&lds_b[n * 136 + kc * 8] =
            *(const f16x8*)&wt[(size_t)(nh * 128 + n) * 128 + kc * 8];
    }
    __syncthreads();

    const int lane = t & 63, wid = t >> 6;
    const int wn0 = wid * 32;
    const int ra = lane & 15, qd = lane >> 4;

    f32x4 acc[7][2];
    #pragma unroll
    for (int mt = 0; mt < 7; ++mt)
        #pragma unroll
        for (int nt = 0; nt < 2; ++nt)
            acc[mt][nt] = (f32x4){0.f, 0.f, 0.f, 0.f};

    #pragma unroll
    for (int ks = 0; ks < 4; ++ks) {
        f16x8 af[7], bf[2];
        #pragma unroll
        for (int mt = 0; mt < 7; ++mt)
            af[mt] = *(const f16x8*)&lds_a[(mt * 16 + ra) * 136 + ks * 32 + qd * 8];
        #pragma unroll
        for (int nt = 0; nt < 2; ++nt)
            bf[nt] = *(const f16x8*)&lds_b[(wn0 + nt * 16 + ra) * 136 + ks * 32 + qd * 8];
        #pragma unroll
        for (int mt = 0; mt < 7; ++mt)
            #pragma unroll
            for (int nt = 0; nt < 2; ++nt)
                acc[mt][nt] = __builtin_amdgcn_mfma_f32_16x16x32_f16(
                    af[mt], bf[nt], acc[mt][nt], 0, 0, 0);
    }
    __syncthreads();

    // ---- BN + f16, transpose via LDS (reuse lds_a as C[m][d]) ----
    f16* lds_c = lds_a;
    const float inv = 1.0f / sqrtf(1.001f);
    #pragma unroll
    for (int nt = 0; nt < 2; ++nt) {
        const int d  = wn0 + nt * 16 + ra;       // block-local col 0..127
        const int dg = nh * 128 + d;             // global col 0..255
        float scale, shift;
        if (dg < 64)       { scale = gq[dg] * inv;        shift = bq[dg]; }
        else if (dg < 128) { scale = gk[dg - 64] * inv;   shift = bk[dg - 64]; }
        else               { scale = gv[dg - 128] * inv;  shift = bv[dg - 128]; }
        #pragma unroll
        for (int mt = 0; mt < 7; ++mt)
            #pragma unroll
            for (int rg = 0; rg < 4; ++rg) {
                const int m = mt * 16 + qd * 4 + rg;
                lds_c[m * 136 + d] = (f16)fmaf(acc[mt][nt][rg], scale, shift);
            }
    }
    __syncthreads();

    if (nh == 0) {
        // q/k: 16B row stores, coalesced
        const int rl = t & 31, gs2 = t >> 5;
        #pragma unroll
        for (int it = 0; it < 4; ++it) {
            const int rem = it * 32 + rl;
            if (rem < MT) {
                #pragma unroll
                for (int half = 0; half < 2; ++half) {
                    const int gslot = half * 8 + gs2;
                    const f16x8 v = *(const f16x8*)&lds_c[rem * 136 + gslot * 8];
                    f16* dst = (gslot < 8) ? qt : kt;
                    const int g = gslot & 7;
                    *(f16x8*)&dst[((size_t)(b * GG + g) * PLANE + rem0 + rem) * 8] = v;
                }
            }
        }
    } else {
        // v -> vt2[bg][J=B28][w][c][jbit]: interleave rows w and w+56
        const int cq = t & 3, w8 = (t >> 2) & 7, g = t >> 5;
        #pragma unroll
        for (int it = 0; it < 7; ++it) {
            const int w = it * 8 + w8;
            const int doff = g * 16 + cq * 4;
            const u32x2 a  = *(const u32x2*)&lds_c[w * 136 + doff];         // j0: c0..c3
            const u32x2 bb = *(const u32x2*)&lds_c[(56 + w) * 136 + doff];  // j1: c0..c3
            uint4 o;
            o.x = __builtin_amdgcn_perm(a.x, bb.x, 0x01000504u);  // c0j0 c0j1
            o.y = __builtin_amdgcn_perm(a.x, bb.x, 0x03020706u);  // c1j0 c1j1
            o.z = __builtin_amdgcn_perm(a.y, bb.y, 0x01000504u);  // c2j0 c2j1
            o.w = __builtin_amdgcn_perm(a.y, bb.y, 0x03020706u);  // c3j0 c3j1
            const size_t base =
                (((size_t)(b * GG + g) * NBLK + B28) * HH + w) * 32 + cq * 8;
            *(uint4*)&vt2[base] = o;
        }
    }
}

// -------------------------------------------------------------------------
// K2: one block per (b, i, g).
// -------------------------------------------------------------------------
__global__ __launch_bounds__(256) void attn_kernel(
    const f16* __restrict__ qt, const f16* __restrict__ kt, const f16* __restrict__ vt2,
    const float* __restrict__ q_rel, const float* __restrict__ k_rel, const float* __restrict__ v_rel,
    const float* __restrict__ g_qk, const float* __restrict__ b_qk,
    const float* __restrict__ g_qr, const float* __restrict__ b_qr,
    const float* __restrict__ g_kr, const float* __restrict__ b_kr,
    const float* __restrict__ g_sv, const float* __restrict__ b_sv,
    const float* __restrict__ g_sve, const float* __restrict__ b_sve,
    float* __restrict__ out)
{
    const int i = blockIdx.x;   // 56
    const int g = blockIdx.y;   // 8
    const int b = blockIdx.z;   // 32
    const int t = threadIdx.x;

    __shared__ float s32[56][57];   // raw scores [j][w]
    __shared__ f16 s16[56 * 58];    // normalized sim, transposed [w][j]
    __shared__ f16 qi[56 * 8];      // q5[b,i,w,g,:]
    __shared__ f16 qe[56 * 8];      // q_emb[i,j,:] = q_rel[i-j+55]
    __shared__ f16 ke[56 * 8];      // k_emb[j,i,:] = k_rel[j-i+55]
    __shared__ f16 ve2[28 * 32];    // v_emb j-pair-interleaved [J][c][jbit]

    const float inv = 1.0f / sqrtf(1.001f);
    const int bg = (b * GG + g) * PLANE;

    // ---- Phase A: stage LDS ----
    if (t < 56)
        *(f16x8*)&qi[t * 8] = *(const f16x8*)&qt[(size_t)(bg + i * HH + t) * 8];
    for (int idx = t; idx < 448; idx += 256) {
        const int j = idx >> 3, c = idx & 7;
        qe[idx] = (f16)q_rel[(i - j + 55) * 8 + c];
        ke[idx] = (f16)k_rel[(j - i + 55) * 8 + c];
    }
    for (int idx = t; idx < 896; idx += 256) {
        const int J = idx >> 5, r = idx & 31, c = r >> 1, jb = r & 1;
        ve2[idx] = (f16)v_rel[(2 * J + jb - i + 55) * 16 + c];
    }
    const float sqk = g_qk[g] * inv, bqk = b_qk[g];
    const float sqr = g_qr[g] * inv, bqr = b_qr[g];
    const float skr = g_kr[g] * inv, bkr = b_kr[g];
    __syncthreads();

    // ---- Phase B: raw scores; wave = 14 j-rows, lane = w; no cross-lane ----
    {
        const int wv = t >> 6, lane = t & 63;
        const int wc = (lane < 56) ? lane : 55;
        const f16x8 qv = *(const f16x8*)&qi[wc * 8];
        for (int jj = 0; jj < 14; ++jj) {
            const int j = wv * 14 + jj;
            const f16x8 kv = *(const f16x8*)&kt[(size_t)(bg + j * HH + wc) * 8];
            const f16x8 ev = *(const f16x8*)&qe[j * 8];   // LDS broadcast
            const f16x8 fv = *(const f16x8*)&ke[j * 8];   // LDS broadcast
            float qk = 0.f, qr = 0.f, kr = 0.f;
            #pragma unroll
            for (int c = 0; c < 4; ++c) {
                const f16x2 kk = ((const f16x2*)&kv)[c];
                const f16x2 qq = ((const f16x2*)&qv)[c];
                qk = __builtin_amdgcn_fdot2(qq, kk, qk, false);
                qr = __builtin_amdgcn_fdot2(qq, ((const f16x2*)&ev)[c], qr, false);
                kr = __builtin_amdgcn_fdot2(kk, ((const f16x2*)&fv)[c], kr, false);
            }
            const float s = fmaf(sqk, qk, bqk) + fmaf(sqr, qr, bqr) + fmaf(skr, kr, bkr);
            if (lane < 56) s32[j][lane] = s;
        }
    }
    __syncthreads();

    // ---- Phase C: softmax per j-row. t<224: j=t>>2, quarter=t&3 (14 w each).
    //      Quad-local reductions only: shfl_xor(1,2) are quad-DPP (VALU). ----
    if (t < 224) {
        const int j = t >> 2, q = t & 3;
        const int w0 = q * 14;
        float v[14];
        #pragma unroll
        for (int wi = 0; wi < 14; ++wi) v[wi] = s32[j][w0 + wi];
        float mx = v[0];
        #pragma unroll
        for (int wi = 1; wi < 14; ++wi) mx = fmaxf(mx, v[wi]);
        mx = fmaxf(mx, __shfl_xor(mx, 1));
        mx = fmaxf(mx, __shfl_xor(mx, 2));
        float e[14];
        float sum = 0.f;
        #pragma unroll
        for (int wi = 0; wi < 14; ++wi) { e[wi] = __expf(v[wi] - mx); sum += e[wi]; }
        sum += __shfl_xor(sum, 1);
        sum += __shfl_xor(sum, 2);
        const float rs = __builtin_amdgcn_rcpf(sum);
        #pragma unroll
        for (int wi = 0; wi < 14; ++wi)
            s16[(w0 + wi) * 58 + j] = (f16)(e[wi] * rs);
    }
    __syncthreads();

    // ---- Phase D: sv + sve via fdot2 over j-pairs. t<224: (w=t/4, cq=t%4) ----
    if (t < 224) {
        const int w = t >> 2, cq = t & 3;
        const f16* vp = vt2 + ((size_t)(b * GG + g) * NBLK * HH + w) * 32 + cq * 8;
        float sv[4] = {0.f, 0.f, 0.f, 0.f};
        float se[4] = {0.f, 0.f, 0.f, 0.f};
        #pragma unroll 2
        for (int J = 0; J < 28; J += 2) {
            const f16x4 pp4 = *(const f16x4*)&s16[w * 58 + 2 * J];   // p for J, J+1
            #pragma unroll
            for (int u = 0; u < 2; ++u) {
                const f16x2 pp = ((const f16x2*)&pp4)[u];
                const f16x8 vl = *(const f16x8*)(vp + (size_t)(J + u) * (HH * 32));
                const f16x8 el = *(const f16x8*)&ve2[(J + u) * 32 + cq * 8];
                #pragma unroll
                for (int c = 0; c < 4; ++c) {
                    sv[c] = __builtin_amdgcn_fdot2(pp, ((const f16x2*)&vl)[c], sv[c], false);
                    se[c] = __builtin_amdgcn_fdot2(pp, ((const f16x2*)&el)[c], se[c], false);
                }
            }
        }
        const int ch = g * 16 + cq * 4;
        const float4 gsv  = *(const float4*)(g_sv + ch);
        const float4 bsv  = *(const float4*)(b_sv + ch);
        const float4 gsve = *(const float4*)(g_sve + ch);
        const float4 bsve = *(const float4*)(b_sve + ch);
        float4 o;
        o.x = fmaf(gsv.x * inv, sv[0], bsv.x) + fmaf(gsve.x * inv, se[0], bsve.x);
        o.y = fmaf(gsv.y * inv, sv[1], bsv.y) + fmaf(gsve.y * inv, se[1], bsve.y);
        o.z = fmaf(gsv.z * inv, sv[2], bsv.z) + fmaf(gsve.z * inv, se[2], bsve.z);
        o.w = fmaf(gsv.w * inv, sv[3], bsv.w) + fmaf(gsve.w * inv, se[3], bsve.w);
        *(float4*)(out + ((size_t)(b * HH + i) * HH + w) * 128 + ch) = o;
    }
}

// -------------------------------------------------------------------------
extern "C" void kernel_launch(void* const* d_in, const int* in_sizes, int n_in,
                              void* d_out, int out_size, void* d_ws, size_t ws_size,
                              hipStream_t stream)
{
    const float* x     = (const float*)d_in[0];
    const float* w_q   = (const float*)d_in[1];
    const float* w_k   = (const float*)d_in[2];
    const float* w_v   = (const float*)d_in[3];
    const float* q_rel = (const float*)d_in[4];
    const float* k_rel = (const float*)d_in[5];
    const float* v_rel = (const float*)d_in[6];
    const float* g_q   = (const float*)d_in[7];
    const float* b_q   = (const float*)d_in[8];
    const float* g_k   = (const float*)d_in[9];
    const float* b_k   = (const float*)d_in[10];
    const float* g_v   = (const float*)d_in[11];
    const float* b_v   = (const float*)d_in[12];
    const float* g_qk  = (const float*)d_in[13];
    const float* b_qk  = (const float*)d_in[14];
    const float* g_qr  = (const float*)d_in[15];
    const float* b_qr  = (const float*)d_in[16];
    const float* g_kr  = (const float*)d_in[17];
    const float* b_kr  = (const float*)d_in[18];
    const float* g_sv  = (const float*)d_in[19];
    const float* b_sv  = (const float*)d_in[20];
    const float* g_sve = (const float*)d_in[21];
    const float* b_sve = (const float*)d_in[22];
    float* out = (float*)d_out;

    // workspace (f16): wt 32768 | qt/kt 6,422,528 each | vt2 12,845,056 (~51.5 MB)
    f16* wt  = (f16*)d_ws;
    f16* qt  = wt + 32768;
    f16* kt  = qt + (size_t)NB * GG * PLANE * 8;
    f16* vt2 = kt + (size_t)NB * GG * PLANE * 8;

    prep_kernel<<<16, 256, 0, stream>>>(w_q, w_k, w_v, wt);

    qkv_kernel<<<dim3((NB * PLANE) / MT, 2), 256, 0, stream>>>(
        x, wt, g_q, b_q, g_k, b_k, g_v, b_v, qt, kt, vt2);

    attn_kernel<<<dim3(56, 8, 32), 256, 0, stream>>>(
        qt, kt, vt2, q_rel, k_rel, v_rel,
        g_qk, b_qk, g_qr, b_qr, g_kr, b_kr, g_sv, b_sv, g_sve, b_sve, out);
}